// Round 7
// baseline (373.603 us; speedup 1.0000x reference)
//
#include <hip/hip_runtime.h>

// PureWaveAttention B=2,T=2048,D=1024,H=16,NW=64,HD=64 — fp32 I/O, all GEMMs
// on MFMA via 2-term fp16 split: a = hi + lo/2048 (lo stored pre-scaled x2048).
// C = hh(hi,hi) + mx(hi,lo + lo,hi)/2048. Rel err 2^-22 -> fp32-equivalent.
// Pipeline:
//  0) xsplit: x fp32 -> xhi/xlo fp16 (aliases G region, dead until chunk_kv)
//  0b) wsplit: W{qf,qp,kf,kp,v,o} fp32[k][n] -> Whi/Wlo fp16[n][k]
//  1) proj: qn/kn = normalize(sin((x@Wf+bf)*t + (x@Wp+bp))) -> fp16
//  2) vgemm: v = x@Wv+bv -> fp32 in d_out (consumed before out-gemm)
//  3) chunk_kv -> G; prefix -> M; attn_chunk -> att split fp16 (aliases qnh/knh)
//  4) outgemm: d_out = att@Wo+bo
// R7: counted-waitcnt barriers (T3/T4). Every prior version plateaued at
// MfmaUtil 32-34% because __syncthreads = s_waitcnt vmcnt(0) lgkmcnt(0) +
// s_barrier drains ALL in-flight loads at each phase boundary.
//  - proj (R5 structure, best measured 136.5us): phase barrier is now
//    {sched_barrier; s_waitcnt vmcnt(4) lgkmcnt(0); s_barrier; sched_barrier}.
//    GLLs are pinned BEFORE A-loads, so vmcnt(4) drains exactly the 4 GLLs
//    feeding the next buffer; the 4 A-prefetch loads stay in flight. Each
//    wave drains its OWN GLLs pre-barrier -> cross-wave LDS data ready.
//  - gemm (R2 structure): barrier is lgkmcnt(0)-only (ds_write visibility);
//    the 8 global prefetch loads stay in flight across the barrier.
// ws (56 MB): Wsplit 24 | qnh 8 | knh 8 | G 16 (xhi/xlo alias G before chunk_kv)

#define Bb 2
#define Tt 2048
#define Dd 1024
#define Hh 16
#define NC 32

typedef _Float16 half_t;
typedef _Float16 half8 __attribute__((ext_vector_type(8)));
typedef _Float16 half4h __attribute__((ext_vector_type(4)));
typedef float f32x16 __attribute__((ext_vector_type(16)));

#define MFMA32(a, b, c) __builtin_amdgcn_mfma_f32_32x32x16_f16((a), (b), (c), 0, 0, 0)

// global_load_lds: per-lane global src, wave-uniform LDS base + lane*16.
#define GLL(G, L) __builtin_amdgcn_global_load_lds(                      \
    (const __attribute__((address_space(1))) void*)(G),                  \
    (__attribute__((address_space(3))) void*)(L), 16, 0, 0)

#define SCHED_FENCE() __builtin_amdgcn_sched_barrier(0)

// phase barrier, leaves up to N vmem ops in flight
#define BAR_VM(N) {                                                      \
    SCHED_FENCE();                                                       \
    asm volatile("s_waitcnt vmcnt(" #N ") lgkmcnt(0)" ::: "memory");     \
    __builtin_amdgcn_s_barrier();                                        \
    SCHED_FENCE(); }

// phase barrier, LDS ordering only (vmem stays in flight)
#define BAR_LG() {                                                       \
    SCHED_FENCE();                                                       \
    asm volatile("s_waitcnt lgkmcnt(0)" ::: "memory");                   \
    __builtin_amdgcn_s_barrier();                                        \
    SCHED_FENCE(); }

// ---------------------------------------------------------------------------
// Kernel -1: split x fp32 -> xhi, xlo fp16 (lo pre-scaled x2048).
// ---------------------------------------------------------------------------
__global__ __launch_bounds__(256) void xsplit_kernel(
    const float* __restrict__ X, half_t* __restrict__ XHI, half_t* __restrict__ XLO)
{
  const size_t i = ((size_t)blockIdx.x * 256 + threadIdx.x) * 8;
  float4 a = *(const float4*)&X[i];
  float4 b = *(const float4*)&X[i + 4];
  const float av[8] = {a.x, a.y, a.z, a.w, b.x, b.y, b.z, b.w};
  half8 hv, lv;
  #pragma unroll
  for (int j = 0; j < 8; ++j) {
    half_t hx = (half_t)av[j];
    hv[j] = hx; lv[j] = (half_t)((av[j] - (float)hx) * 2048.f);
  }
  *(half8*)&XHI[i] = hv;
  *(half8*)&XLO[i] = lv;
}

// ---------------------------------------------------------------------------
// Kernel 0: split+transpose weights: W[k][n] fp32 -> hi[n][k], lo[n][k] fp16.
// Per matrix: hi at m*2097152 halves, lo at +1048576.
// ---------------------------------------------------------------------------
__global__ __launch_bounds__(256) void wsplit_kernel(
    const float* __restrict__ W0, const float* __restrict__ W1,
    const float* __restrict__ W2, const float* __restrict__ W3,
    const float* __restrict__ W4, const float* __restrict__ W5,
    half_t* __restrict__ WSP)
{
  __shared__ float Ld[64][68];
  const int tid = threadIdx.x;
  const int m = blockIdx.z;
  const float* W = (m == 0) ? W0 : (m == 1) ? W1 : (m == 2) ? W2
                 : (m == 3) ? W3 : (m == 4) ? W4 : W5;
  const int k0 = blockIdx.x * 64, n0 = blockIdx.y * 64;
  const int r = tid >> 2, c4 = (tid & 3) * 16;
  #pragma unroll
  for (int i = 0; i < 4; ++i)
    *(float4*)&Ld[r][c4 + i * 4] =
        *(const float4*)&W[(size_t)(k0 + r) * Dd + n0 + c4 + i * 4];
  __syncthreads();
  half_t* hi = WSP + (size_t)m * 2097152;
  half_t* lo = hi + 1048576;
  const int n = tid >> 2, kc = (tid & 3) * 16;
  half8 hv0, hv1, lv0, lv1;
  #pragma unroll
  for (int i = 0; i < 8; ++i) {
    float v0 = Ld[kc + i][n];
    half_t h0 = (half_t)v0;
    hv0[i] = h0; lv0[i] = (half_t)((v0 - (float)h0) * 2048.f);
    float v1 = Ld[kc + 8 + i][n];
    half_t h1 = (half_t)v1;
    hv1[i] = h1; lv1[i] = (half_t)((v1 - (float)h1) * 2048.f);
  }
  *(half8*)&hi[(size_t)(n0 + n) * Dd + k0 + kc]     = hv0;
  *(half8*)&hi[(size_t)(n0 + n) * Dd + k0 + kc + 8] = hv1;
  *(half8*)&lo[(size_t)(n0 + n) * Dd + k0 + kc]     = lv0;
  *(half8*)&lo[(size_t)(n0 + n) * Dd + k0 + kc + 8] = lv1;
}

// ---------------------------------------------------------------------------
// Kernel 1: proj. Block = 128 t-rows x (64 F | 64 P) cols for head h, pair p.
// Wave w: A rows 32w..+31 in REGISTERS; B dbuf in LDS via global_load_lds.
// Per 32-k phase: {STAGE next B (4 GLL) | pin | LOADA next A (4 loads) |
// 24 MFMA | BAR_VM(4)}. vmcnt(4) drains the GLLs, keeps A-loads in flight.
// B LDS tile: [128 rows][64 halves]; row = 8x16B chunks [hi oct0..3|lo 0..3],
// chunk c at phys c^(row&7); per-lane GLOBAL source pre-swizzled to match.
// ---------------------------------------------------------------------------
__global__ __launch_bounds__(256, 2) void proj_kernel(
    const half_t* __restrict__ XHI, const half_t* __restrict__ XLO,
    const half_t* __restrict__ WSP,
    const float* __restrict__ bqf, const float* __restrict__ bqp,
    const float* __restrict__ bkf, const float* __restrict__ bkp,
    half_t* __restrict__ QNH, half_t* __restrict__ KNH)
{
  __shared__ __align__(16) half_t Bs[2][128][64];
  const int tid = threadIdx.x;
  const int mb = blockIdx.x, h = blockIdx.y;
  const int b = blockIdx.z >> 1, p = blockIdx.z & 1;
  const int t0 = mb * 128, row0 = b * Tt + t0, col0 = h * 64;
  const half_t* WF = WSP + (size_t)(2 * p) * 2097152;      // hi; lo at +1048576
  const half_t* WP = WSP + (size_t)(2 * p + 1) * 2097152;
  const float* BF = p ? bkf : bqf;
  const float* BP = p ? bkp : bqp;
  half_t* OUTH = p ? KNH : QNH;

  f32x16 hh[4], mx[4];
  #pragma unroll
  for (int i = 0; i < 4; ++i) { hh[i] = (f32x16)(0.f); mx[i] = (f32x16)(0.f); }

  const int lane = tid & 63, w = tid >> 6;
  const int rl = lane & 31, kq = lane >> 5;
  const int sw = rl & 7;

  // A (x) fragment sources: lane owns row 32w+rl, k-octets kq and 2+kq.
  const half_t* aHi = XHI + (size_t)(row0 + 32 * w + rl) * Dd + kq * 8;
  const half_t* aLo = XLO + (size_t)(row0 + 32 * w + rl) * Dd + kq * 8;

  // B staging sources (per-lane, inverse-swizzled chunk):
  const int lr8 = lane >> 3;                 // row-within-8
  const int lcc = (lane & 7) ^ lr8;          // logical chunk this lane fetches
  const int csel = (lcc & 3) * 8;            // k sub-offset (halves)
  const size_t loOff = (lcc >= 4) ? 1048576 : 0;
  const half_t* gb0 = WF + loOff + (size_t)(col0 + 8 * w + lr8) * Dd + csel;
  const half_t* gb1 = gb0 + 32 * Dd;
  const half_t* gb2 = WP + loOff + (size_t)(col0 + 8 * w + lr8) * Dd + csel;
  const half_t* gb3 = gb2 + 32 * Dd;

#define STAGE_PB(BI, K) {                          \
    GLL(gb0 + (K), &Bs[BI][8 * w][0]);             \
    GLL(gb1 + (K), &Bs[BI][32 + 8 * w][0]);        \
    GLL(gb2 + (K), &Bs[BI][64 + 8 * w][0]);        \
    GLL(gb3 + (K), &Bs[BI][96 + 8 * w][0]);        \
    SCHED_FENCE(); }

#define LOADA(H0, H1, L0, L1, K) {                 \
    H0 = *(const half8*)&aHi[(K)];                 \
    H1 = *(const half8*)&aHi[(K) + 16];            \
    L0 = *(const half8*)&aLo[(K)];                 \
    L1 = *(const half8*)&aLo[(K) + 16]; }

#define KT_P(H0, H1, L0, L1, BI) {                                     \
    { const int c0 = (kq ^ sw) * 8, c1 = ((4 + kq) ^ sw) * 8;          \
      _Pragma("unroll")                                                \
      for (int tn = 0; tn < 4; ++tn) {                                 \
        half8 bh = *(const half8*)&Bs[BI][32 * tn + rl][c0];           \
        half8 bl = *(const half8*)&Bs[BI][32 * tn + rl][c1];           \
        hh[tn] = MFMA32(H0, bh, hh[tn]);                               \
        mx[tn] = MFMA32(H0, bl, mx[tn]);                               \
        mx[tn] = MFMA32(L0, bh, mx[tn]); } }                           \
    { const int c0 = (((2 + kq)) ^ sw) * 8, c1 = ((6 + kq) ^ sw) * 8;  \
      _Pragma("unroll")                                                \
      for (int tn = 0; tn < 4; ++tn) {                                 \
        half8 bh = *(const half8*)&Bs[BI][32 * tn + rl][c0];           \
        half8 bl = *(const half8*)&Bs[BI][32 * tn + rl][c1];           \
        hh[tn] = MFMA32(H1, bh, hh[tn]);                               \
        mx[tn] = MFMA32(H1, bl, mx[tn]);                               \
        mx[tn] = MFMA32(L1, bh, mx[tn]); } } }

  half8 ah0c, ah1c, al0c, al1c, ah0n, ah1n, al0n, al1n;
  STAGE_PB(0, 0)
  LOADA(ah0c, ah1c, al0c, al1c, 0)
  BAR_VM(4)

  #pragma unroll 1
  for (int k0 = 0; k0 < Dd; k0 += 64) {
    if (k0 + 32 < Dd) { STAGE_PB(1, k0 + 32) LOADA(ah0n, ah1n, al0n, al1n, k0 + 32) }
    KT_P(ah0c, ah1c, al0c, al1c, 0)
    BAR_VM(4)
    if (k0 + 64 < Dd) { STAGE_PB(0, k0 + 64) LOADA(ah0c, ah1c, al0c, al1c, k0 + 64) }
    KT_P(ah0n, ah1n, al0n, al1n, 1)
    BAR_VM(4)
  }
#undef STAGE_PB
#undef LOADA
#undef KT_P

  const float bf0 = BF[col0 + rl], bf1 = BF[col0 + 32 + rl];
  const float bp0 = BP[col0 + rl], bp1 = BP[col0 + 32 + rl];
  #pragma unroll
  for (int j = 0; j < 16; ++j) {
    const int rtj = (j & 3) + 8 * (j >> 2) + 4 * kq;  // row within 32-tile
    const float tf = (float)(t0 + 32 * w + rtj);
    float f0 = hh[0][j] + mx[0][j] * (1.f / 2048.f) + bf0;
    float f1 = hh[1][j] + mx[1][j] * (1.f / 2048.f) + bf1;
    float p0 = hh[2][j] + mx[2][j] * (1.f / 2048.f) + bp0;
    float p1 = hh[3][j] + mx[3][j] * (1.f / 2048.f) + bp1;
    float w0 = sinf(fmaf(f0, tf, p0));
    float w1 = sinf(fmaf(f1, tf, p1));
    float ss = w0 * w0 + w1 * w1;
    ss += __shfl_xor(ss, 1); ss += __shfl_xor(ss, 2);
    ss += __shfl_xor(ss, 4); ss += __shfl_xor(ss, 8);
    ss += __shfl_xor(ss, 16);
    const float inv = 1.f / fmaxf(sqrtf(ss), 1e-12f);
    half_t* op = &OUTH[((size_t)(b * Tt) + t0 + 32 * w + rtj) * Dd + col0];
    op[rl]      = (half_t)(w0 * inv);
    op[32 + rl] = (half_t)(w1 * inv);
  }
}

// ---------------------------------------------------------------------------
// Kernel 2/4: GEMM OUT[4096,1024] = A@W + bias. R2 structure (128x128 dbuf,
// row-per-thread ds_write staging, XOR-swz) with lgkm-only barriers: the 8
// global prefetch loads stay in flight across phase boundaries.
// ---------------------------------------------------------------------------
__global__ __launch_bounds__(256, 2) void gemm_kernel(
    const half_t* __restrict__ AHI, const half_t* __restrict__ ALO,
    const half_t* __restrict__ WHI,
    const float* __restrict__ BIAS, float* __restrict__ OUT)
{
  __shared__ __align__(16) half_t As[2][128][64];
  __shared__ __align__(16) half_t Bs[2][128][64];
  const int tid = threadIdx.x;
  const int m0 = blockIdx.x * 128, n0 = blockIdx.y * 128;

  f32x16 hh[4], mx[4];
  #pragma unroll
  for (int i = 0; i < 4; ++i) { hh[i] = (f32x16)(0.f); mx[i] = (f32x16)(0.f); }

  const int lane = tid & 63, w = tid >> 6;
  const int rl = lane & 31, kq = lane >> 5;
  const int sw = rl & 7;

  const int r = tid & 127, isB = tid >> 7;
  const int swr = r & 7;
  const half_t* srcHi = isB ? &WHI[(size_t)(n0 + r) * Dd]
                            : &AHI[(size_t)(m0 + r) * Dd];
  const half_t* srcLo = isB ? &WHI[1048576 + (size_t)(n0 + r) * Dd]
                            : &ALO[(size_t)(m0 + r) * Dd];
  half_t* dstRow = isB ? &Bs[0][r][0] : &As[0][r][0];
  const int pc0 = (0 ^ swr) * 8, pc1 = (1 ^ swr) * 8;
  const int pc2 = (2 ^ swr) * 8, pc3 = (3 ^ swr) * 8;
  const int pc4 = (4 ^ swr) * 8, pc5 = (5 ^ swr) * 8;
  const int pc6 = (6 ^ swr) * 8, pc7 = (7 ^ swr) * 8;

  half8 rg0, rg1, rg2, rg3, rg4, rg5, rg6, rg7;

#define G_LOADREGS(K)                                                          \
  rg0 = *(const half8*)&srcHi[(K)];      rg1 = *(const half8*)&srcHi[(K) + 8]; \
  rg2 = *(const half8*)&srcHi[(K) + 16]; rg3 = *(const half8*)&srcHi[(K) + 24];\
  rg4 = *(const half8*)&srcLo[(K)];      rg5 = *(const half8*)&srcLo[(K) + 8]; \
  rg6 = *(const half8*)&srcLo[(K) + 16]; rg7 = *(const half8*)&srcLo[(K) + 24];

#define G_WRITE(BI) {                                                     \
  half_t* d_ = dstRow + (BI) * 8192;                                      \
  *(half8*)&d_[pc0] = rg0; *(half8*)&d_[pc1] = rg1;                       \
  *(half8*)&d_[pc2] = rg2; *(half8*)&d_[pc3] = rg3;                       \
  *(half8*)&d_[pc4] = rg4; *(half8*)&d_[pc5] = rg5;                       \
  *(half8*)&d_[pc6] = rg6; *(half8*)&d_[pc7] = rg7; }

#define G_KT(BI)                                                          \
  _Pragma("unroll")                                                       \
  for (int ks = 0; ks < 2; ++ks) {                                        \
    half8 ahi = *(const half8*)&As[BI][32 * w + rl][((2 * ks + kq) ^ sw) * 8];       \
    half8 alo = *(const half8*)&As[BI][32 * w + rl][((4 + 2 * ks + kq) ^ sw) * 8];   \
    _Pragma("unroll")                                                     \
    for (int tn = 0; tn < 4; ++tn) {                                      \
      half8 bhi = *(const half8*)&Bs[BI][32 * tn + rl][((2 * ks + kq) ^ sw) * 8];    \
      half8 blo = *(const half8*)&Bs[BI][32 * tn + rl][((4 + 2 * ks + kq) ^ sw) * 8];\
      hh[tn] = MFMA32(ahi, bhi, hh[tn]);                                  \
      mx[tn] = MFMA32(ahi, blo, mx[tn]);                                  \
      mx[tn] = MFMA32(alo, bhi, mx[tn]);                                  \
    }                                                                     \
  }

  G_LOADREGS(0)
  G_WRITE(0)
  G_LOADREGS(32)
  BAR_LG()

  #pragma unroll 1
  for (int k0 = 0; k0 < Dd; k0 += 64) {
    G_KT(0)
    G_WRITE(1)
    if (k0 + 64 < Dd) { G_LOADREGS(k0 + 64) }
    BAR_LG()
    G_KT(1)
    if (k0 + 64 < Dd) { G_WRITE(0) }
    if (k0 + 96 < Dd) { G_LOADREGS(k0 + 96) }
    BAR_LG()
  }
#undef G_LOADREGS
#undef G_WRITE
#undef G_KT

  const float bb0 = BIAS[n0 + rl],      bb1 = BIAS[n0 + 32 + rl];
  const float bb2 = BIAS[n0 + 64 + rl], bb3 = BIAS[n0 + 96 + rl];
  #pragma unroll
  for (int j = 0; j < 16; ++j) {
    const int rtj = (j & 3) + 8 * (j >> 2) + 4 * kq;
    float* orow = &OUT[(size_t)(m0 + 32 * w + rtj) * Dd + n0];
    orow[rl]      = hh[0][j] + mx[0][j] * (1.f / 2048.f) + bb0;
    orow[32 + rl] = hh[1][j] + mx[1][j] * (1.f / 2048.f) + bb1;
    orow[64 + rl] = hh[2][j] + mx[2][j] * (1.f / 2048.f) + bb2;
    orow[96 + rl] = hh[3][j] + mx[3][j] * (1.f / 2048.f) + bb3;
  }
}

// ---------------------------------------------------------------------------
// Kernel 3a: G_c[w][d] = sum_{s in c} K[s][w]*V[s][d]. K from fp16, V fp32.
// ---------------------------------------------------------------------------
__global__ __launch_bounds__(256) void chunk_kv_kernel(
    const half_t* __restrict__ KNH, const float* __restrict__ V,
    float* __restrict__ G)
{
  __shared__ float Ks[64][64];
  __shared__ float Vs[64][64];
  const int tid = threadIdx.x;
  const int c = blockIdx.x, h = blockIdx.y, b = blockIdx.z;
  const int s0 = c * 64;
  const int lr = tid >> 2, lc = (tid & 3) * 16;
  {
    const half_t* krow = &KNH[(size_t)(b * Tt + s0 + lr) * Dd + h * 64 + lc];
    half8 ka = *(const half8*)&krow[0];
    half8 kb = *(const half8*)&krow[8];
    #pragma unroll
    for (int i = 0; i < 8; ++i) {
      Ks[lr][lc + i] = (float)ka[i];
      Ks[lr][lc + 8 + i] = (float)kb[i];
    }
    const float* vrow = &V[(size_t)(b * Tt + s0 + lr) * Dd + h * 64 + lc];
    #pragma unroll
    for (int i = 0; i < 4; ++i)
      *(float4*)&Vs[lr][lc + i * 4] = *(const float4*)&vrow[i * 4];
  }
  __syncthreads();

  const int ty = tid >> 4, tx = tid & 15;
  float g[4][4] = {{0.f}};
  #pragma unroll 4
  for (int s = 0; s < 64; ++s) {
    float4 kv = *(const float4*)&Ks[s][ty * 4];
    float4 vv = *(const float4*)&Vs[s][tx * 4];
    const float* k_ = (const float*)&kv;
    const float* v_ = (const float*)&vv;
    #pragma unroll
    for (int i = 0; i < 4; ++i)
      #pragma unroll
      for (int j = 0; j < 4; ++j)
        g[i][j] = fmaf(k_[i], v_[j], g[i][j]);
  }
  float* Gp = G + (((size_t)(b * Hh + h) * NC + c) << 12);
  #pragma unroll
  for (int i = 0; i < 4; ++i)
    *(float4*)&Gp[(ty * 4 + i) * 64 + tx * 4] =
        make_float4(g[i][0], g[i][1], g[i][2], g[i][3]);
}

// ---------------------------------------------------------------------------
// Kernel 3b: in-place exclusive prefix over NC chunk matrices per (b,h).
// 512 blocks; thread = 1 float, fully coalesced.
// ---------------------------------------------------------------------------
__global__ __launch_bounds__(256) void prefix_kernel(float* __restrict__ G)
{
  const int seg = blockIdx.x, h = blockIdx.y, b = blockIdx.z;
  float* base = G + (((size_t)(b * Hh + h) * NC) << 12) + seg * 256 + threadIdx.x;
  float acc = 0.f;
  #pragma unroll 4
  for (int c = 0; c < NC; ++c) {
    float* p = base + ((size_t)c << 12);
    const float g = *p;
    *p = acc;
    acc += g;
  }
}

// ---------------------------------------------------------------------------
// Kernel 3c: O_c = (Q_c M_c + tril(Q_c K_c^T) V_c) * scale/sqrt(t+1).
// Q,K from fp16; out split to fp16 hi/lo (lo x2048), aliasing qnh/knh.
// ---------------------------------------------------------------------------
__global__ __launch_bounds__(256) void attn_chunk_kernel(
    const half_t* __restrict__ QNH, const half_t* __restrict__ KNH,
    const float* __restrict__ V, const float* __restrict__ M,
    const float* __restrict__ SCALE,
    half_t* __restrict__ ATTHI, half_t* __restrict__ ATTLO)
{
  __shared__ float Qt[64][68];
  __shared__ float Kt[64][68];
  __shared__ float SM[64][68];
  __shared__ float Vs[64][64];
  const int tid = threadIdx.x;
  const int c = blockIdx.x, h = blockIdx.y, b = blockIdx.z;
  const int t0 = c * 64;
  const int lr = tid >> 2, lc = (tid & 3) * 16;
  {
    const half_t* qrow = &QNH[(size_t)(b * Tt + t0 + lr) * Dd + h * 64 + lc];
    const half_t* krow = &KNH[(size_t)(b * Tt + t0 + lr) * Dd + h * 64 + lc];
    half8 qa = *(const half8*)&qrow[0];
    half8 qb = *(const half8*)&qrow[8];
    half8 ka = *(const half8*)&krow[0];
    half8 kb = *(const half8*)&krow[8];
    #pragma unroll
    for (int i = 0; i < 8; ++i) {
      Qt[lc + i][lr] = (float)qa[i];     Qt[lc + 8 + i][lr] = (float)qb[i];
      Kt[lc + i][lr] = (float)ka[i];     Kt[lc + 8 + i][lr] = (float)kb[i];
    }
    const float* vrow = &V[(size_t)(b * Tt + t0 + lr) * Dd + h * 64 + lc];
    const float* mrow = &M[(((size_t)(b * Hh + h) * NC + c) << 12) + lr * 64 + lc];
    #pragma unroll
    for (int i = 0; i < 4; ++i) {
      *(float4*)&Vs[lr][lc + i * 4] = *(const float4*)&vrow[i * 4];
      *(float4*)&SM[lr][lc + i * 4] = *(const float4*)&mrow[i * 4];
    }
  }
  __syncthreads();

  const int ty = tid >> 4, tx = tid & 15;
  float o[4][4] = {{0.f}};
  float sc[4][4] = {{0.f}};

  #pragma unroll 4
  for (int w = 0; w < 64; ++w) {
    float4 qv = *(const float4*)&Qt[w][ty * 4];
    float4 mv = *(const float4*)&SM[w][tx * 4];
    float4 kv = *(const float4*)&Kt[w][tx * 4];
    const float* q_ = (const float*)&qv;
    const float* m_ = (const float*)&mv;
    const float* k_ = (const float*)&kv;
    #pragma unroll
    for (int i = 0; i < 4; ++i) {
      float qq = q_[i];
      #pragma unroll
      for (int j = 0; j < 4; ++j) {
        o[i][j]  = fmaf(qq, m_[j], o[i][j]);
        sc[i][j] = fmaf(qq, k_[j], sc[i][j]);
      }
    }
  }
  __syncthreads();

  #pragma unroll
  for (int i = 0; i < 4; ++i) {
    const int lt = ty * 4 + i;
    #pragma unroll
    for (int j = 0; j < 4; ++j) {
      const int ls = tx * 4 + j;
      SM[ls][lt] = (ls <= lt) ? sc[i][j] : 0.f;
    }
  }
  __syncthreads();

  #pragma unroll 4
  for (int s = 0; s < 64; ++s) {
    float4 sv = *(const float4*)&SM[s][ty * 4];
    float4 vv = *(const float4*)&Vs[s][tx * 4];
    const float* s_ = (const float*)&sv;
    const float* v_ = (const float*)&vv;
    #pragma unroll
    for (int i = 0; i < 4; ++i)
      #pragma unroll
      for (int j = 0; j < 4; ++j)
        o[i][j] = fmaf(s_[i], v_[j], o[i][j]);
  }

  const float sch = SCALE[h];
  #pragma unroll
  for (int i = 0; i < 4; ++i) {
    const int t = t0 + ty * 4 + i;
    const float fac = sch / sqrtf((float)(t + 1));
    half4h hv, lv;
    #pragma unroll
    for (int j = 0; j < 4; ++j) {
      float v = o[i][j] * fac;
      half_t hx = (half_t)v;
      hv[j] = hx; lv[j] = (half_t)((v - (float)hx) * 2048.f);
    }
    *(half4h*)&ATTHI[(size_t)(b * Tt + t) * Dd + h * 64 + tx * 4] = hv;
    *(half4h*)&ATTLO[(size_t)(b * Tt + t) * Dd + h * 64 + tx * 4] = lv;
  }
}

// ---------------------------------------------------------------------------
extern "C" void kernel_launch(void* const* d_in, const int* in_sizes, int n_in,
                              void* d_out, int out_size, void* d_ws, size_t ws_size,
                              hipStream_t stream) {
  const float* x   = (const float*)d_in[0];
  const float* Wqf = (const float*)d_in[1];
  const float* bqf = (const float*)d_in[2];
  const float* Wkf = (const float*)d_in[3];
  const float* bkf = (const float*)d_in[4];
  const float* Wqp = (const float*)d_in[5];
  const float* bqp = (const float*)d_in[6];
  const float* Wkp = (const float*)d_in[7];
  const float* bkp = (const float*)d_in[8];
  const float* Wv  = (const float*)d_in[9];
  const float* bv  = (const float*)d_in[10];
  const float* Wo  = (const float*)d_in[11];
  const float* bo  = (const float*)d_in[12];
  const float* scale = (const float*)d_in[13];

  // ws layout (56 MB): Wsplit 24 MB | qnh 8 MB | knh 8 MB | G 16 MB
  half_t* WSP = (half_t*)d_ws;                 // 6 mats x (hi 1M + lo 1M) halves
  half_t* qnh = WSP + 12582912;                // 4,194,304 halves
  half_t* knh = qnh + 4194304;
  float*  G   = (float*)(knh + 4194304);
  half_t* xhi = (half_t*)G;                    // x halves alias G: dead before
  half_t* xlo = xhi + 4194304;                 // chunk_kv writes G
  float*  vbuf = (float*)d_out;                // v lives in d_out, consumed
                                               // before the final out-gemm

  xsplit_kernel<<<dim3(2048), 256, 0, stream>>>(x, xhi, xlo);

  // mat order in WSP: 0=qf 1=qp 2=kf 3=kp 4=v 5=o
  wsplit_kernel<<<dim3(16, 16, 6), 256, 0, stream>>>(Wqf, Wqp, Wkf, Wkp, Wv, Wo, WSP);

  proj_kernel<<<dim3(Tt / 128, Hh, Bb * 2), 256, 0, stream>>>(
      xhi, xlo, WSP, bqf, bqp, bkf, bkp, qnh, knh);

  gemm_kernel<<<dim3((Bb * Tt) / 128, Dd / 128), 256, 0, stream>>>(
      xhi, xlo, WSP + (size_t)4 * 2097152, bv, vbuf);

  chunk_kv_kernel<<<dim3(NC, Hh, Bb), 256, 0, stream>>>(knh, vbuf, G);
  prefix_kernel<<<dim3(16, Hh, Bb), 256, 0, stream>>>(G);
  attn_chunk_kernel<<<dim3(NC, Hh, Bb), 256, 0, stream>>>(
      qnh, knh, vbuf, G, scale, qnh /*atthi*/, knh /*attlo*/);

  gemm_kernel<<<dim3((Bb * Tt) / 128, Dd / 128), 256, 0, stream>>>(
      qnh, knh, WSP + (size_t)5 * 2097152, bo, (float*)d_out);
}

// Round 8
// 360.537 us; speedup vs baseline: 1.0362x; 1.0362x over previous
//
#include <hip/hip_runtime.h>

// PureWaveAttention B=2,T=2048,D=1024,H=16,NW=64,HD=64 — fp32 I/O, all GEMMs
// on MFMA via 2-term fp16 split: a = hi + lo/2048 (lo stored pre-scaled x2048).
// C = hh(hi,hi) + mx(hi,lo + lo,hi)/2048. Rel err 2^-22 -> fp32-equivalent.
// Pipeline:
//  0) xsplit: x fp32 -> xhi/xlo fp16 (aliases G region, dead until chunk_kv)
//  0b) wsplit: W{qf,qp,kf,kp,v,o} fp32[k][n] -> Whi/Wlo fp16[n][k]
//  1) proj: qn/kn = normalize(sin((x@Wf+bf)*t + (x@Wp+bp))) -> fp16
//  2) vgemm: v = x@Wv+bv -> fp32 in d_out (consumed before out-gemm)
//  3) chunk_kv -> G; prefix -> M; attn_chunk -> att split fp16 (aliases qnh/knh)
//  4) outgemm: d_out = att@Wo+bo
// R8: proj QUAD-buffer. Ledger: R5 dbuf+sync=136.5, R6 BK64=141.9, R7
// vmcnt+schedfence=148.4. R7 failed because (a) sched_barrier(0) pinning
// (m141) and (b) with dbuf the needed GLL is same-phase -> counting can't
// add cover. Quad-buffer: phase p computes buf[p%4], stages buf[(p+2)%4]
// -> each GLL in flight across 2 phases (~L3 latency). Barrier =
// {s_waitcnt vmcnt(4) lgkmcnt(0); s_barrier}, NO sched fences; per-phase
// issue order LOADA then GLL so in-order vmcnt(4) leaves exactly this
// phase's GLLs in flight and drains everything older. Tail hand-checked.
// gemm: R7's BAR_LG version (measured best: rest 229->225).
// ws (56 MB): Wsplit 24 | qnh 8 | knh 8 | G 16 (xhi/xlo alias G before chunk_kv)

#define Bb 2
#define Tt 2048
#define Dd 1024
#define Hh 16
#define NC 32

typedef _Float16 half_t;
typedef _Float16 half8 __attribute__((ext_vector_type(8)));
typedef _Float16 half4h __attribute__((ext_vector_type(4)));
typedef float f32x16 __attribute__((ext_vector_type(16)));

#define MFMA32(a, b, c) __builtin_amdgcn_mfma_f32_32x32x16_f16((a), (b), (c), 0, 0, 0)

// global_load_lds: per-lane global src, wave-uniform LDS base + lane*16.
#define GLL(G, L) __builtin_amdgcn_global_load_lds(                      \
    (const __attribute__((address_space(1))) void*)(G),                  \
    (__attribute__((address_space(3))) void*)(L), 16, 0, 0)

#define SCHED_FENCE() __builtin_amdgcn_sched_barrier(0)

// proj phase barrier: drain all but the 4 newest vmem ops (= this phase's
// GLLs). No sched fences (R7 lesson).
#define BARC() {                                                         \
    asm volatile("s_waitcnt vmcnt(4) lgkmcnt(0)" ::: "memory");          \
    __builtin_amdgcn_s_barrier(); }

// gemm phase barrier, LDS ordering only (vmem stays in flight) — R7 version.
#define BAR_LG() {                                                       \
    SCHED_FENCE();                                                       \
    asm volatile("s_waitcnt lgkmcnt(0)" ::: "memory");                   \
    __builtin_amdgcn_s_barrier();                                        \
    SCHED_FENCE(); }

// ---------------------------------------------------------------------------
// Kernel -1: split x fp32 -> xhi, xlo fp16 (lo pre-scaled x2048).
// ---------------------------------------------------------------------------
__global__ __launch_bounds__(256) void xsplit_kernel(
    const float* __restrict__ X, half_t* __restrict__ XHI, half_t* __restrict__ XLO)
{
  const size_t i = ((size_t)blockIdx.x * 256 + threadIdx.x) * 8;
  float4 a = *(const float4*)&X[i];
  float4 b = *(const float4*)&X[i + 4];
  const float av[8] = {a.x, a.y, a.z, a.w, b.x, b.y, b.z, b.w};
  half8 hv, lv;
  #pragma unroll
  for (int j = 0; j < 8; ++j) {
    half_t hx = (half_t)av[j];
    hv[j] = hx; lv[j] = (half_t)((av[j] - (float)hx) * 2048.f);
  }
  *(half8*)&XHI[i] = hv;
  *(half8*)&XLO[i] = lv;
}

// ---------------------------------------------------------------------------
// Kernel 0: split+transpose weights: W[k][n] fp32 -> hi[n][k], lo[n][k] fp16.
// Per matrix: hi at m*2097152 halves, lo at +1048576.
// ---------------------------------------------------------------------------
__global__ __launch_bounds__(256) void wsplit_kernel(
    const float* __restrict__ W0, const float* __restrict__ W1,
    const float* __restrict__ W2, const float* __restrict__ W3,
    const float* __restrict__ W4, const float* __restrict__ W5,
    half_t* __restrict__ WSP)
{
  __shared__ float Ld[64][68];
  const int tid = threadIdx.x;
  const int m = blockIdx.z;
  const float* W = (m == 0) ? W0 : (m == 1) ? W1 : (m == 2) ? W2
                 : (m == 3) ? W3 : (m == 4) ? W4 : W5;
  const int k0 = blockIdx.x * 64, n0 = blockIdx.y * 64;
  const int r = tid >> 2, c4 = (tid & 3) * 16;
  #pragma unroll
  for (int i = 0; i < 4; ++i)
    *(float4*)&Ld[r][c4 + i * 4] =
        *(const float4*)&W[(size_t)(k0 + r) * Dd + n0 + c4 + i * 4];
  __syncthreads();
  half_t* hi = WSP + (size_t)m * 2097152;
  half_t* lo = hi + 1048576;
  const int n = tid >> 2, kc = (tid & 3) * 16;
  half8 hv0, hv1, lv0, lv1;
  #pragma unroll
  for (int i = 0; i < 8; ++i) {
    float v0 = Ld[kc + i][n];
    half_t h0 = (half_t)v0;
    hv0[i] = h0; lv0[i] = (half_t)((v0 - (float)h0) * 2048.f);
    float v1 = Ld[kc + 8 + i][n];
    half_t h1 = (half_t)v1;
    hv1[i] = h1; lv1[i] = (half_t)((v1 - (float)h1) * 2048.f);
  }
  *(half8*)&hi[(size_t)(n0 + n) * Dd + k0 + kc]     = hv0;
  *(half8*)&hi[(size_t)(n0 + n) * Dd + k0 + kc + 8] = hv1;
  *(half8*)&lo[(size_t)(n0 + n) * Dd + k0 + kc]     = lv0;
  *(half8*)&lo[(size_t)(n0 + n) * Dd + k0 + kc + 8] = lv1;
}

// ---------------------------------------------------------------------------
// Kernel 1: proj. Block = 128 t-rows x (64 F | 64 P) cols for head h, pair p.
// Wave w: A rows 32w..+31 in REGISTERS; B QUAD-buffered in LDS via
// global_load_lds (stage 2 phases ahead). Phase: {LOADA A(p+1) | STAGE GLL
// buf(p+2) | 24 MFMA on buf(p%4) | BARC vmcnt(4)}.
// B LDS tile: [128 rows][64 halves]; row = 8x16B chunks [hi oct0..3|lo 0..3],
// chunk c at phys c^(row&7); per-lane GLOBAL source pre-swizzled to match.
// ---------------------------------------------------------------------------
__global__ __launch_bounds__(256, 2) void proj_kernel(
    const half_t* __restrict__ XHI, const half_t* __restrict__ XLO,
    const half_t* __restrict__ WSP,
    const float* __restrict__ bqf, const float* __restrict__ bqp,
    const float* __restrict__ bkf, const float* __restrict__ bkp,
    half_t* __restrict__ QNH, half_t* __restrict__ KNH)
{
  __shared__ __align__(16) half_t Bs[4][128][64];
  const int tid = threadIdx.x;
  const int mb = blockIdx.x, h = blockIdx.y;
  const int b = blockIdx.z >> 1, p = blockIdx.z & 1;
  const int t0 = mb * 128, row0 = b * Tt + t0, col0 = h * 64;
  const half_t* WF = WSP + (size_t)(2 * p) * 2097152;      // hi; lo at +1048576
  const half_t* WP = WSP + (size_t)(2 * p + 1) * 2097152;
  const float* BF = p ? bkf : bqf;
  const float* BP = p ? bkp : bqp;
  half_t* OUTH = p ? KNH : QNH;

  f32x16 hh[4], mx[4];
  #pragma unroll
  for (int i = 0; i < 4; ++i) { hh[i] = (f32x16)(0.f); mx[i] = (f32x16)(0.f); }

  const int lane = tid & 63, w = tid >> 6;
  const int rl = lane & 31, kq = lane >> 5;
  const int sw = rl & 7;

  // A (x) fragment sources: lane owns row 32w+rl, k-octets kq and 2+kq.
  const half_t* aHi = XHI + (size_t)(row0 + 32 * w + rl) * Dd + kq * 8;
  const half_t* aLo = XLO + (size_t)(row0 + 32 * w + rl) * Dd + kq * 8;

  // B staging sources (per-lane, inverse-swizzled chunk):
  const int lr8 = lane >> 3;                 // row-within-8
  const int lcc = (lane & 7) ^ lr8;          // logical chunk this lane fetches
  const int csel = (lcc & 3) * 8;            // k sub-offset (halves)
  const size_t loOff = (lcc >= 4) ? 1048576 : 0;
  const half_t* gb0 = WF + loOff + (size_t)(col0 + 8 * w + lr8) * Dd + csel;
  const half_t* gb1 = gb0 + 32 * Dd;
  const half_t* gb2 = WP + loOff + (size_t)(col0 + 8 * w + lr8) * Dd + csel;
  const half_t* gb3 = gb2 + 32 * Dd;

#define STAGE_PB(BI, K) {                          \
    GLL(gb0 + (K), &Bs[BI][8 * w][0]);             \
    GLL(gb1 + (K), &Bs[BI][32 + 8 * w][0]);        \
    GLL(gb2 + (K), &Bs[BI][64 + 8 * w][0]);        \
    GLL(gb3 + (K), &Bs[BI][96 + 8 * w][0]); }

#define LOADA(H0, H1, L0, L1, K) {                 \
    H0 = *(const half8*)&aHi[(K)];                 \
    H1 = *(const half8*)&aHi[(K) + 16];            \
    L0 = *(const half8*)&aLo[(K)];                 \
    L1 = *(const half8*)&aLo[(K) + 16]; }

#define KT_P(H0, H1, L0, L1, BI) {                                     \
    { const int c0 = (kq ^ sw) * 8, c1 = ((4 + kq) ^ sw) * 8;          \
      _Pragma("unroll")                                                \
      for (int tn = 0; tn < 4; ++tn) {                                 \
        half8 bh = *(const half8*)&Bs[BI][32 * tn + rl][c0];           \
        half8 bl = *(const half8*)&Bs[BI][32 * tn + rl][c1];           \
        hh[tn] = MFMA32(H0, bh, hh[tn]);                               \
        mx[tn] = MFMA32(H0, bl, mx[tn]);                               \
        mx[tn] = MFMA32(L0, bh, mx[tn]); } }                           \
    { const int c0 = (((2 + kq)) ^ sw) * 8, c1 = ((6 + kq) ^ sw) * 8;  \
      _Pragma("unroll")                                                \
      for (int tn = 0; tn < 4; ++tn) {                                 \
        half8 bh = *(const half8*)&Bs[BI][32 * tn + rl][c0];           \
        half8 bl = *(const half8*)&Bs[BI][32 * tn + rl][c1];           \
        hh[tn] = MFMA32(H1, bh, hh[tn]);                               \
        mx[tn] = MFMA32(H1, bl, mx[tn]);                               \
        mx[tn] = MFMA32(L1, bh, mx[tn]); } } }

  half8 ah0c, ah1c, al0c, al1c, ah0n, ah1n, al0n, al1n;
  // prologue: stage buf0,buf1; load A(k=0). vmcnt(4) leaves A in flight,
  // drains GLL0+GLL1 (buf0 needed now; buf1 loses cover once — ok).
  STAGE_PB(0, 0)
  STAGE_PB(1, 32)
  LOADA(ah0c, ah1c, al0c, al1c, 0)
  BARC()

  #pragma unroll 1
  for (int k0 = 0; k0 < Dd; k0 += 128) {      // 4 phases (32-k each) per iter
    // phase a: compute buf0 (k0); A(k0+32); stage buf2 (k0+64)
    LOADA(ah0n, ah1n, al0n, al1n, k0 + 32)
    STAGE_PB(2, k0 + 64)
    KT_P(ah0c, ah1c, al0c, al1c, 0)
    BARC()
    // phase b: compute buf1 (k0+32); A(k0+64); stage buf3 (k0+96)
    LOADA(ah0c, ah1c, al0c, al1c, k0 + 64)
    STAGE_PB(3, k0 + 96)
    KT_P(ah0n, ah1n, al0n, al1n, 1)
    BARC()
    // phase c: compute buf2 (k0+64); A(k0+96); stage buf0 (k0+128)
    LOADA(ah0n, ah1n, al0n, al1n, k0 + 96)
    if (k0 + 128 < Dd) { STAGE_PB(0, k0 + 128) }
    KT_P(ah0c, ah1c, al0c, al1c, 2)
    BARC()
    // phase d: compute buf3 (k0+96); A(k0+128); stage buf1 (k0+160)
    if (k0 + 128 < Dd) { LOADA(ah0c, ah1c, al0c, al1c, k0 + 128) }
    if (k0 + 160 < Dd) { STAGE_PB(1, k0 + 160) }
    KT_P(ah0n, ah1n, al0n, al1n, 3)
    BARC()
  }
#undef STAGE_PB
#undef LOADA
#undef KT_P

  const float bf0 = BF[col0 + rl], bf1 = BF[col0 + 32 + rl];
  const float bp0 = BP[col0 + rl], bp1 = BP[col0 + 32 + rl];
  #pragma unroll
  for (int j = 0; j < 16; ++j) {
    const int rtj = (j & 3) + 8 * (j >> 2) + 4 * kq;  // row within 32-tile
    const float tf = (float)(t0 + 32 * w + rtj);
    float f0 = hh[0][j] + mx[0][j] * (1.f / 2048.f) + bf0;
    float f1 = hh[1][j] + mx[1][j] * (1.f / 2048.f) + bf1;
    float p0 = hh[2][j] + mx[2][j] * (1.f / 2048.f) + bp0;
    float p1 = hh[3][j] + mx[3][j] * (1.f / 2048.f) + bp1;
    float w0 = sinf(fmaf(f0, tf, p0));
    float w1 = sinf(fmaf(f1, tf, p1));
    float ss = w0 * w0 + w1 * w1;
    ss += __shfl_xor(ss, 1); ss += __shfl_xor(ss, 2);
    ss += __shfl_xor(ss, 4); ss += __shfl_xor(ss, 8);
    ss += __shfl_xor(ss, 16);
    const float inv = 1.f / fmaxf(sqrtf(ss), 1e-12f);
    half_t* op = &OUTH[((size_t)(b * Tt) + t0 + 32 * w + rtj) * Dd + col0];
    op[rl]      = (half_t)(w0 * inv);
    op[32 + rl] = (half_t)(w1 * inv);
  }
}

// ---------------------------------------------------------------------------
// Kernel 2/4: GEMM OUT[4096,1024] = A@W + bias. R2 structure (128x128 dbuf,
// row-per-thread ds_write staging, XOR-swz) with lgkm-only barriers: the 8
// global prefetch loads stay in flight across phase boundaries. (R7, kept.)
// ---------------------------------------------------------------------------
__global__ __launch_bounds__(256, 2) void gemm_kernel(
    const half_t* __restrict__ AHI, const half_t* __restrict__ ALO,
    const half_t* __restrict__ WHI,
    const float* __restrict__ BIAS, float* __restrict__ OUT)
{
  __shared__ __align__(16) half_t As[2][128][64];
  __shared__ __align__(16) half_t Bs[2][128][64];
  const int tid = threadIdx.x;
  const int m0 = blockIdx.x * 128, n0 = blockIdx.y * 128;

  f32x16 hh[4], mx[4];
  #pragma unroll
  for (int i = 0; i < 4; ++i) { hh[i] = (f32x16)(0.f); mx[i] = (f32x16)(0.f); }

  const int lane = tid & 63, w = tid >> 6;
  const int rl = lane & 31, kq = lane >> 5;
  const int sw = rl & 7;

  const int r = tid & 127, isB = tid >> 7;
  const int swr = r & 7;
  const half_t* srcHi = isB ? &WHI[(size_t)(n0 + r) * Dd]
                            : &AHI[(size_t)(m0 + r) * Dd];
  const half_t* srcLo = isB ? &WHI[1048576 + (size_t)(n0 + r) * Dd]
                            : &ALO[(size_t)(m0 + r) * Dd];
  half_t* dstRow = isB ? &Bs[0][r][0] : &As[0][r][0];
  const int pc0 = (0 ^ swr) * 8, pc1 = (1 ^ swr) * 8;
  const int pc2 = (2 ^ swr) * 8, pc3 = (3 ^ swr) * 8;
  const int pc4 = (4 ^ swr) * 8, pc5 = (5 ^ swr) * 8;
  const int pc6 = (6 ^ swr) * 8, pc7 = (7 ^ swr) * 8;

  half8 rg0, rg1, rg2, rg3, rg4, rg5, rg6, rg7;

#define G_LOADREGS(K)                                                          \
  rg0 = *(const half8*)&srcHi[(K)];      rg1 = *(const half8*)&srcHi[(K) + 8]; \
  rg2 = *(const half8*)&srcHi[(K) + 16]; rg3 = *(const half8*)&srcHi[(K) + 24];\
  rg4 = *(const half8*)&srcLo[(K)];      rg5 = *(const half8*)&srcLo[(K) + 8]; \
  rg6 = *(const half8*)&srcLo[(K) + 16]; rg7 = *(const half8*)&srcLo[(K) + 24];

#define G_WRITE(BI) {                                                     \
  half_t* d_ = dstRow + (BI) * 8192;                                      \
  *(half8*)&d_[pc0] = rg0; *(half8*)&d_[pc1] = rg1;                       \
  *(half8*)&d_[pc2] = rg2; *(half8*)&d_[pc3] = rg3;                       \
  *(half8*)&d_[pc4] = rg4; *(half8*)&d_[pc5] = rg5;                       \
  *(half8*)&d_[pc6] = rg6; *(half8*)&d_[pc7] = rg7; }

#define G_KT(BI)                                                          \
  _Pragma("unroll")                                                       \
  for (int ks = 0; ks < 2; ++ks) {                                        \
    half8 ahi = *(const half8*)&As[BI][32 * w + rl][((2 * ks + kq) ^ sw) * 8];       \
    half8 alo = *(const half8*)&As[BI][32 * w + rl][((4 + 2 * ks + kq) ^ sw) * 8];   \
    _Pragma("unroll")                                                     \
    for (int tn = 0; tn < 4; ++tn) {                                      \
      half8 bhi = *(const half8*)&Bs[BI][32 * tn + rl][((2 * ks + kq) ^ sw) * 8];    \
      half8 blo = *(const half8*)&Bs[BI][32 * tn + rl][((4 + 2 * ks + kq) ^ sw) * 8];\
      hh[tn] = MFMA32(ahi, bhi, hh[tn]);                                  \
      mx[tn] = MFMA32(ahi, blo, mx[tn]);                                  \
      mx[tn] = MFMA32(alo, bhi, mx[tn]);                                  \
    }                                                                     \
  }

  G_LOADREGS(0)
  G_WRITE(0)
  G_LOADREGS(32)
  BAR_LG()

  #pragma unroll 1
  for (int k0 = 0; k0 < Dd; k0 += 64) {
    G_KT(0)
    G_WRITE(1)
    if (k0 + 64 < Dd) { G_LOADREGS(k0 + 64) }
    BAR_LG()
    G_KT(1)
    if (k0 + 64 < Dd) { G_WRITE(0) }
    if (k0 + 96 < Dd) { G_LOADREGS(k0 + 96) }
    BAR_LG()
  }
#undef G_LOADREGS
#undef G_WRITE
#undef G_KT

  const float bb0 = BIAS[n0 + rl],      bb1 = BIAS[n0 + 32 + rl];
  const float bb2 = BIAS[n0 + 64 + rl], bb3 = BIAS[n0 + 96 + rl];
  #pragma unroll
  for (int j = 0; j < 16; ++j) {
    const int rtj = (j & 3) + 8 * (j >> 2) + 4 * kq;
    float* orow = &OUT[(size_t)(m0 + 32 * w + rtj) * Dd + n0];
    orow[rl]      = hh[0][j] + mx[0][j] * (1.f / 2048.f) + bb0;
    orow[32 + rl] = hh[1][j] + mx[1][j] * (1.f / 2048.f) + bb1;
    orow[64 + rl] = hh[2][j] + mx[2][j] * (1.f / 2048.f) + bb2;
    orow[96 + rl] = hh[3][j] + mx[3][j] * (1.f / 2048.f) + bb3;
  }
}

// ---------------------------------------------------------------------------
// Kernel 3a: G_c[w][d] = sum_{s in c} K[s][w]*V[s][d]. K from fp16, V fp32.
// ---------------------------------------------------------------------------
__global__ __launch_bounds__(256) void chunk_kv_kernel(
    const half_t* __restrict__ KNH, const float* __restrict__ V,
    float* __restrict__ G)
{
  __shared__ float Ks[64][64];
  __shared__ float Vs[64][64];
  const int tid = threadIdx.x;
  const int c = blockIdx.x, h = blockIdx.y, b = blockIdx.z;
  const int s0 = c * 64;
  const int lr = tid >> 2, lc = (tid & 3) * 16;
  {
    const half_t* krow = &KNH[(size_t)(b * Tt + s0 + lr) * Dd + h * 64 + lc];
    half8 ka = *(const half8*)&krow[0];
    half8 kb = *(const half8*)&krow[8];
    #pragma unroll
    for (int i = 0; i < 8; ++i) {
      Ks[lr][lc + i] = (float)ka[i];
      Ks[lr][lc + 8 + i] = (float)kb[i];
    }
    const float* vrow = &V[(size_t)(b * Tt + s0 + lr) * Dd + h * 64 + lc];
    #pragma unroll
    for (int i = 0; i < 4; ++i)
      *(float4*)&Vs[lr][lc + i * 4] = *(const float4*)&vrow[i * 4];
  }
  __syncthreads();

  const int ty = tid >> 4, tx = tid & 15;
  float g[4][4] = {{0.f}};
  #pragma unroll 4
  for (int s = 0; s < 64; ++s) {
    float4 kv = *(const float4*)&Ks[s][ty * 4];
    float4 vv = *(const float4*)&Vs[s][tx * 4];
    const float* k_ = (const float*)&kv;
    const float* v_ = (const float*)&vv;
    #pragma unroll
    for (int i = 0; i < 4; ++i)
      #pragma unroll
      for (int j = 0; j < 4; ++j)
        g[i][j] = fmaf(k_[i], v_[j], g[i][j]);
  }
  float* Gp = G + (((size_t)(b * Hh + h) * NC + c) << 12);
  #pragma unroll
  for (int i = 0; i < 4; ++i)
    *(float4*)&Gp[(ty * 4 + i) * 64 + tx * 4] =
        make_float4(g[i][0], g[i][1], g[i][2], g[i][3]);
}

// ---------------------------------------------------------------------------
// Kernel 3b: in-place exclusive prefix over NC chunk matrices per (b,h).
// 512 blocks; thread = 1 float, fully coalesced.
// ---------------------------------------------------------------------------
__global__ __launch_bounds__(256) void prefix_kernel(float* __restrict__ G)
{
  const int seg = blockIdx.x, h = blockIdx.y, b = blockIdx.z;
  float* base = G + (((size_t)(b * Hh + h) * NC) << 12) + seg * 256 + threadIdx.x;
  float acc = 0.f;
  #pragma unroll 4
  for (int c = 0; c < NC; ++c) {
    float* p = base + ((size_t)c << 12);
    const float g = *p;
    *p = acc;
    acc += g;
  }
}

// ---------------------------------------------------------------------------
// Kernel 3c: O_c = (Q_c M_c + tril(Q_c K_c^T) V_c) * scale/sqrt(t+1).
// Q,K from fp16; out split to fp16 hi/lo (lo x2048), aliasing qnh/knh.
// ---------------------------------------------------------------------------
__global__ __launch_bounds__(256) void attn_chunk_kernel(
    const half_t* __restrict__ QNH, const half_t* __restrict__ KNH,
    const float* __restrict__ V, const float* __restrict__ M,
    const float* __restrict__ SCALE,
    half_t* __restrict__ ATTHI, half_t* __restrict__ ATTLO)
{
  __shared__ float Qt[64][68];
  __shared__ float Kt[64][68];
  __shared__ float SM[64][68];
  __shared__ float Vs[64][64];
  const int tid = threadIdx.x;
  const int c = blockIdx.x, h = blockIdx.y, b = blockIdx.z;
  const int t0 = c * 64;
  const int lr = tid >> 2, lc = (tid & 3) * 16;
  {
    const half_t* qrow = &QNH[(size_t)(b * Tt + t0 + lr) * Dd + h * 64 + lc];
    const half_t* krow = &KNH[(size_t)(b * Tt + t0 + lr) * Dd + h * 64 + lc];
    half8 qa = *(const half8*)&qrow[0];
    half8 qb = *(const half8*)&qrow[8];
    half8 ka = *(const half8*)&krow[0];
    half8 kb = *(const half8*)&krow[8];
    #pragma unroll
    for (int i = 0; i < 8; ++i) {
      Qt[lc + i][lr] = (float)qa[i];     Qt[lc + 8 + i][lr] = (float)qb[i];
      Kt[lc + i][lr] = (float)ka[i];     Kt[lc + 8 + i][lr] = (float)kb[i];
    }
    const float* vrow = &V[(size_t)(b * Tt + t0 + lr) * Dd + h * 64 + lc];
    const float* mrow = &M[(((size_t)(b * Hh + h) * NC + c) << 12) + lr * 64 + lc];
    #pragma unroll
    for (int i = 0; i < 4; ++i) {
      *(float4*)&Vs[lr][lc + i * 4] = *(const float4*)&vrow[i * 4];
      *(float4*)&SM[lr][lc + i * 4] = *(const float4*)&mrow[i * 4];
    }
  }
  __syncthreads();

  const int ty = tid >> 4, tx = tid & 15;
  float o[4][4] = {{0.f}};
  float sc[4][4] = {{0.f}};

  #pragma unroll 4
  for (int w = 0; w < 64; ++w) {
    float4 qv = *(const float4*)&Qt[w][ty * 4];
    float4 mv = *(const float4*)&SM[w][tx * 4];
    float4 kv = *(const float4*)&Kt[w][tx * 4];
    const float* q_ = (const float*)&qv;
    const float* m_ = (const float*)&mv;
    const float* k_ = (const float*)&kv;
    #pragma unroll
    for (int i = 0; i < 4; ++i) {
      float qq = q_[i];
      #pragma unroll
      for (int j = 0; j < 4; ++j) {
        o[i][j]  = fmaf(qq, m_[j], o[i][j]);
        sc[i][j] = fmaf(qq, k_[j], sc[i][j]);
      }
    }
  }
  __syncthreads();

  #pragma unroll
  for (int i = 0; i < 4; ++i) {
    const int lt = ty * 4 + i;
    #pragma unroll
    for (int j = 0; j < 4; ++j) {
      const int ls = tx * 4 + j;
      SM[ls][lt] = (ls <= lt) ? sc[i][j] : 0.f;
    }
  }
  __syncthreads();

  #pragma unroll 4
  for (int s = 0; s < 64; ++s) {
    float4 sv = *(const float4*)&SM[s][ty * 4];
    float4 vv = *(const float4*)&Vs[s][tx * 4];
    const float* s_ = (const float*)&sv;
    const float* v_ = (const float*)&vv;
    #pragma unroll
    for (int i = 0; i < 4; ++i)
      #pragma unroll
      for (int j = 0; j < 4; ++j)
        o[i][j] = fmaf(s_[i], v_[j], o[i][j]);
  }

  const float sch = SCALE[h];
  #pragma unroll
  for (int i = 0; i < 4; ++i) {
    const int t = t0 + ty * 4 + i;
    const float fac = sch / sqrtf((float)(t + 1));
    half4h hv, lv;
    #pragma unroll
    for (int j = 0; j < 4; ++j) {
      float v = o[i][j] * fac;
      half_t hx = (half_t)v;
      hv[j] = hx; lv[j] = (half_t)((v - (float)hx) * 2048.f);
    }
    *(half4h*)&ATTHI[(size_t)(b * Tt + t) * Dd + h * 64 + tx * 4] = hv;
    *(half4h*)&ATTLO[(size_t)(b * Tt + t) * Dd + h * 64 + tx * 4] = lv;
  }
}

// ---------------------------------------------------------------------------
extern "C" void kernel_launch(void* const* d_in, const int* in_sizes, int n_in,
                              void* d_out, int out_size, void* d_ws, size_t ws_size,
                              hipStream_t stream) {
  const float* x   = (const float*)d_in[0];
  const float* Wqf = (const float*)d_in[1];
  const float* bqf = (const float*)d_in[2];
  const float* Wkf = (const float*)d_in[3];
  const float* bkf = (const float*)d_in[4];
  const float* Wqp = (const float*)d_in[5];
  const float* bqp = (const float*)d_in[6];
  const float* Wkp = (const float*)d_in[7];
  const float* bkp = (const float*)d_in[8];
  const float* Wv  = (const float*)d_in[9];
  const float* bv  = (const float*)d_in[10];
  const float* Wo  = (const float*)d_in[11];
  const float* bo  = (const float*)d_in[12];
  const float* scale = (const float*)d_in[13];

  // ws layout (56 MB): Wsplit 24 MB | qnh 8 MB | knh 8 MB | G 16 MB
  half_t* WSP = (half_t*)d_ws;                 // 6 mats x (hi 1M + lo 1M) halves
  half_t* qnh = WSP + 12582912;                // 4,194,304 halves
  half_t* knh = qnh + 4194304;
  float*  G   = (float*)(knh + 4194304);
  half_t* xhi = (half_t*)G;                    // x halves alias G: dead before
  half_t* xlo = xhi + 4194304;                 // chunk_kv writes G
  float*  vbuf = (float*)d_out;                // v lives in d_out, consumed
                                               // before the final out-gemm

  xsplit_kernel<<<dim3(2048), 256, 0, stream>>>(x, xhi, xlo);

  // mat order in WSP: 0=qf 1=qp 2=kf 3=kp 4=v 5=o
  wsplit_kernel<<<dim3(16, 16, 6), 256, 0, stream>>>(Wqf, Wqp, Wkf, Wkp, Wv, Wo, WSP);

  proj_kernel<<<dim3(Tt / 128, Hh, Bb * 2), 256, 0, stream>>>(
      xhi, xlo, WSP, bqf, bqp, bkf, bkp, qnh, knh);

  gemm_kernel<<<dim3((Bb * Tt) / 128, Dd / 128), 256, 0, stream>>>(
      xhi, xlo, WSP + (size_t)4 * 2097152, bv, vbuf);

  chunk_kv_kernel<<<dim3(NC, Hh, Bb), 256, 0, stream>>>(knh, vbuf, G);
  prefix_kernel<<<dim3(16, Hh, Bb), 256, 0, stream>>>(G);
  attn_chunk_kernel<<<dim3(NC, Hh, Bb), 256, 0, stream>>>(
      qnh, knh, vbuf, G, scale, qnh /*atthi*/, knh /*attlo*/);

  gemm_kernel<<<dim3((Bb * Tt) / 128, Dd / 128), 256, 0, stream>>>(
      qnh, knh, WSP + (size_t)5 * 2097152, bo, (float*)d_out);
}